// Round 1
// baseline (111.074 us; speedup 1.0000x reference)
//
#include <hip/hip_runtime.h>

#define HH 128
#define WW 128
#define CC 64
#define OO 64
#define NC 35
#define NPIX (HH*WW)

// Kernel 1: per 64-pixel half-row tile:
//   - compute conv scalar s per pixel (pos channels are closed-form + pl/pr reads)
//   - stage xh = x + s into LDS [c][p] (stride 65 -> conflict-free)
//   - argmax over 35 layout channels (wave 0, coalesced)
//   - per-pixel 64x64 matvec: lane = output channel o, W rows streamed coalesced from L2
//   - transpose y through LDS for coalesced (b,o,h,w) stores
//   - block-reduced per-(b,o) sum/sumsq -> atomicAdd into ws
__global__ __launch_bounds__(256) void ky_kernel(
    const float* __restrict__ x, const float* __restrict__ layout,
    const float* __restrict__ pr, const float* __restrict__ cw,
    const float* __restrict__ cb, const float* __restrict__ Wt,
    const float* __restrict__ bt, const float* __restrict__ pl,
    float* __restrict__ out, float* __restrict__ sums)
{
    __shared__ float s_xh[64*65];   // [c][p], stride 65
    __shared__ float s_y[64*65];    // [p][o], stride 65
    __shared__ int   s_arg[64];
    __shared__ float s_red[4][64][2];

    const int t    = threadIdx.x;
    const int wv   = t >> 6;
    const int lane = t & 63;
    const int tile = blockIdx.x;          // 512 tiles: b(2) x h(128) x whalf(2)
    const int b    = tile >> 8;
    const int rem  = tile & 255;
    const int h    = rem >> 1;
    const int w0   = (rem & 1) << 6;
    const int w    = w0 + lane;

    // ---- conv scalar s for pixel (h, w) ----
    float pxv = (float)h * (2.0f/128.0f) - 1.0f;          // pa ch0: varies with h
    float pyv = (float)w * (2.0f/128.0f) - 1.0f;          // pa ch1: varies with w
    float pl0 = pl[h*WW + w];
    float pl1 = pl[NPIX + h*WW + w];
    float pr0 = pr[((b*2+0)*HH + h)*WW + w];
    float pr1 = pr[((b*2+1)*HH + h)*WW + w];
    int kx = w % 3, kyy = h % 3;
    const float C1 = -0.5f, S1 = 0.86602540378443864676f; // cos/sin(2pi/3)
    float xcv = (kx==0)  ? 1.0f : C1;
    float xsv = (kx==0)  ? 0.0f : ((kx==1)  ? S1 : -S1);
    float ycv = (kyy==0) ? 1.0f : C1;
    float ysv = (kyy==0) ? 0.0f : ((kyy==1) ? S1 : -S1);
    float s = cb[0] + pxv*cw[0] + pyv*cw[1] + pl0*cw[2] + pl1*cw[3]
            + pr0*cw[4] + pr1*cw[5] + xcv*cw[6] + xsv*cw[7] + ycv*cw[8] + ysv*cw[9];

    // ---- stage xh = x + s into LDS (coalesced global reads) ----
    #pragma unroll
    for (int k = 0; k < 16; ++k) {
        int c = wv*16 + k;
        s_xh[c*65 + lane] = x[((b*CC + c)*HH + h)*WW + w] + s;
    }

    // ---- argmax over layout channels (first occurrence of max) ----
    if (wv == 0) {
        const float* lp = layout + ((size_t)b*NC*HH + h)*WW + w;
        float best = lp[0]; int bi = 0;
        #pragma unroll
        for (int c = 1; c < NC; ++c) {
            float v = lp[(size_t)c*NPIX];
            if (v > best) { best = v; bi = c; }
        }
        s_arg[lane] = bi;
    }
    __syncthreads();

    // ---- matvec: each wave handles 16 pixels; lane = output channel o ----
    float sum_ = 0.f, ss_ = 0.f;
    for (int i = 0; i < 16; ++i) {
        int p = wv*16 + i;
        int l = s_arg[p];
        const float* Wl   = Wt + l*4096;
        const float* xcol = s_xh + p;
        float acc = bt[l*64 + lane];
        #pragma unroll 16
        for (int c = 0; c < 64; ++c)
            acc = fmaf(xcol[c*65], Wl[c*64 + lane], acc);
        s_y[p*65 + lane] = acc;
        sum_ += acc;
        ss_  += acc*acc;
    }
    s_red[wv][lane][0] = sum_;
    s_red[wv][lane][1] = ss_;
    __syncthreads();

    // ---- coalesced store of y in (b,o,h,w) layout ----
    #pragma unroll
    for (int i = 0; i < 16; ++i) {
        int o = wv*16 + i;
        out[((b*OO + o)*HH + h)*WW + w0 + lane] = s_y[lane*65 + o];
    }

    // ---- per-block stat reduction -> global atomics ----
    if (wv == 0) {
        float S  = s_red[0][lane][0] + s_red[1][lane][0] + s_red[2][lane][0] + s_red[3][lane][0];
        float SS = s_red[0][lane][1] + s_red[1][lane][1] + s_red[2][lane][1] + s_red[3][lane][1];
        atomicAdd(&sums[(b*OO + lane)*2 + 0], S);
        atomicAdd(&sums[(b*OO + lane)*2 + 1], SS);
    }
}

// Kernel 2: in-place instance norm + leaky relu, float4 elementwise
__global__ __launch_bounds__(256) void norm_kernel(
    float* __restrict__ out, const float* __restrict__ sums)
{
    int idx = blockIdx.x * 256 + threadIdx.x;   // float4 index; 524288 total
    float4* o4 = reinterpret_cast<float4*>(out);
    float4 v = o4[idx];
    int bo = idx >> 12;                          // 4096 float4 per (b,o) row
    float S  = sums[bo*2 + 0];
    float SS = sums[bo*2 + 1];
    const float invN = 1.0f/16384.0f;
    float mean = S * invN;
    float var  = SS * invN - mean*mean;
    float r    = rsqrtf(var + 1e-5f);
    float a;
    a = (v.x - mean) * r; v.x = (a >= 0.f) ? a : 0.01f*a;
    a = (v.y - mean) * r; v.y = (a >= 0.f) ? a : 0.01f*a;
    a = (v.z - mean) * r; v.z = (a >= 0.f) ? a : 0.01f*a;
    a = (v.w - mean) * r; v.w = (a >= 0.f) ? a : 0.01f*a;
    o4[idx] = v;
}

extern "C" void kernel_launch(void* const* d_in, const int* in_sizes, int n_in,
                              void* d_out, int out_size, void* d_ws, size_t ws_size,
                              hipStream_t stream) {
    const float* x      = (const float*)d_in[0];
    const float* layout = (const float*)d_in[1];
    const float* pr     = (const float*)d_in[2];
    const float* cw     = (const float*)d_in[3];
    const float* cb     = (const float*)d_in[4];
    const float* Wt     = (const float*)d_in[5];
    const float* bt     = (const float*)d_in[6];
    const float* pl     = (const float*)d_in[7];
    float* out  = (float*)d_out;
    float* sums = (float*)d_ws;                 // 2*64*2 floats = 1 KB

    hipMemsetAsync(sums, 0, 2*OO*2*sizeof(float), stream);
    ky_kernel<<<512, 256, 0, stream>>>(x, layout, pr, cw, cb, Wt, bt, pl, out, sums);
    norm_kernel<<<2048, 256, 0, stream>>>(out, sums);
}

// Round 2
// 102.801 us; speedup vs baseline: 1.0805x; 1.0805x over previous
//
#include <hip/hip_runtime.h>

#define HH 128
#define WW 128
#define CC 64
#define OO 64
#define NC 35
#define NPIX (HH*WW)
#define NBLK 1024          // ky grid: b(2) x h(128) x wq(4), 32 pixels each

// Kernel 1: per 32-pixel tile.
//  - wave0 lanes<32 compute conv scalar s; wave1 lanes<32 compute argmax
//  - all threads stage raw x into LDS [c][p] stride 33 (conflict-free)
//  - matvec: whole wave per pixel; float4 W loads fetch 4 rows x 64 o per
//    instruction (1 KB/wave, coalesced); lane i -> o-quad 4*(i&15), rows
//    4t+(i>>4); shfl_xor(16,32) reduces across row groups
//  - y transposed through LDS [o][p] stride 33 -> coalesced stores
//  - per-block partial sum/sumsq written to ws (no atomics, no memset)
__global__ __launch_bounds__(256) void ky_kernel(
    const float* __restrict__ x, const float* __restrict__ layout,
    const float* __restrict__ pr, const float* __restrict__ cw,
    const float* __restrict__ cb, const float* __restrict__ Wt,
    const float* __restrict__ bt, const float* __restrict__ pl,
    float* __restrict__ out, float* __restrict__ psum, float* __restrict__ pss)
{
    __shared__ float s_xh[64*33];     // [c][p]
    __shared__ float s_y[64*33];      // [o][p]
    __shared__ float s_s[32];
    __shared__ int   s_arg[32];
    __shared__ float s_red[4][64][2];

    const int t    = threadIdx.x;
    const int wv   = t >> 6;
    const int lane = t & 63;
    const int i15  = lane & 15;
    const int ihi  = lane >> 4;
    const int tile = blockIdx.x;
    const int b    = tile >> 9;
    const int rem  = tile & 511;
    const int h    = rem >> 2;
    const int w0   = (rem & 3) << 5;

    // ---- conv scalar s for 32 pixels (wave 0, lanes 0..31) ----
    if (wv == 0 && lane < 32) {
        int w = w0 + lane;
        float pxv = (float)h * (2.0f/128.0f) - 1.0f;
        float pyv = (float)w * (2.0f/128.0f) - 1.0f;
        float pl0 = pl[h*WW + w];
        float pl1 = pl[NPIX + h*WW + w];
        float pr0 = pr[((b*2+0)*HH + h)*WW + w];
        float pr1 = pr[((b*2+1)*HH + h)*WW + w];
        int kx = w % 3, kyy = h % 3;
        const float C1 = -0.5f, S1 = 0.86602540378443864676f;
        float xcv = (kx==0)  ? 1.0f : C1;
        float xsv = (kx==0)  ? 0.0f : ((kx==1)  ? S1 : -S1);
        float ycv = (kyy==0) ? 1.0f : C1;
        float ysv = (kyy==0) ? 0.0f : ((kyy==1) ? S1 : -S1);
        s_s[lane] = cb[0] + pxv*cw[0] + pyv*cw[1] + pl0*cw[2] + pl1*cw[3]
                  + pr0*cw[4] + pr1*cw[5] + xcv*cw[6] + xsv*cw[7]
                  + ycv*cw[8] + ysv*cw[9];
    }

    // ---- argmax over layout channels (wave 1, lanes 0..31) ----
    if (wv == 1 && lane < 32) {
        int w = w0 + lane;
        const float* lp = layout + ((size_t)(b*NC)*HH + h)*WW + w;
        float best = lp[0]; int bi = 0;
        #pragma unroll
        for (int c = 1; c < NC; ++c) {
            float v = lp[(size_t)c*NPIX];
            if (v > best) { best = v; bi = c; }
        }
        s_arg[lane] = bi;
    }

    // ---- stage raw x into LDS (coalesced) ----
    {
        int p = t & 31, c0 = t >> 5;
        const float* xp = x + ((size_t)(b*CC)*HH + h)*WW + w0 + p;
        #pragma unroll
        for (int k = 0; k < 8; ++k) {
            int c = c0 + 8*k;
            s_xh[c*33 + p] = xp[(size_t)c*NPIX];
        }
    }
    __syncthreads();

    // ---- matvec: each wave handles 8 pixels; whole wave per pixel ----
    float4 sumv = {0,0,0,0}, ssv = {0,0,0,0};
    for (int i = 0; i < 8; ++i) {
        int p = wv*8 + i;
        int l = s_arg[p];
        float sp = s_s[p];
        const float4* W4 = (const float4*)(Wt + l*4096) + lane;
        float4 a = {0,0,0,0};
        #pragma unroll
        for (int tt = 0; tt < 16; ++tt) {
            float4 q  = W4[tt*64];                       // rows 4tt..4tt+3
            float  xv = s_xh[(4*tt + ihi)*33 + p] + sp;  // broadcast read
            a.x = fmaf(xv, q.x, a.x);
            a.y = fmaf(xv, q.y, a.y);
            a.z = fmaf(xv, q.z, a.z);
            a.w = fmaf(xv, q.w, a.w);
        }
        a.x += __shfl_xor(a.x, 16); a.y += __shfl_xor(a.y, 16);
        a.z += __shfl_xor(a.z, 16); a.w += __shfl_xor(a.w, 16);
        a.x += __shfl_xor(a.x, 32); a.y += __shfl_xor(a.y, 32);
        a.z += __shfl_xor(a.z, 32); a.w += __shfl_xor(a.w, 32);
        if (ihi == 0) {
            float4 bq = ((const float4*)(bt + l*64))[i15];
            float y0 = a.x + bq.x, y1 = a.y + bq.y;
            float y2 = a.z + bq.z, y3 = a.w + bq.w;
            int o = 4*i15;
            s_y[(o+0)*33 + p] = y0;
            s_y[(o+1)*33 + p] = y1;
            s_y[(o+2)*33 + p] = y2;
            s_y[(o+3)*33 + p] = y3;
            sumv.x += y0; ssv.x += y0*y0;
            sumv.y += y1; ssv.y += y1*y1;
            sumv.z += y2; ssv.z += y2*y2;
            sumv.w += y3; ssv.w += y3*y3;
        }
    }
    if (ihi == 0) {
        int o = 4*i15;
        s_red[wv][o+0][0] = sumv.x; s_red[wv][o+0][1] = ssv.x;
        s_red[wv][o+1][0] = sumv.y; s_red[wv][o+1][1] = ssv.y;
        s_red[wv][o+2][0] = sumv.z; s_red[wv][o+2][1] = ssv.z;
        s_red[wv][o+3][0] = sumv.w; s_red[wv][o+3][1] = ssv.w;
    }
    __syncthreads();

    // ---- coalesced store of y in (b,o,h,w) layout ----
    {
        int p = t & 31, o0 = t >> 5;
        float* op = out + ((size_t)(b*OO)*HH + h)*WW + w0 + p;
        #pragma unroll
        for (int k = 0; k < 8; ++k) {
            int o = o0 + 8*k;
            op[(size_t)o*NPIX] = s_y[o*33 + p];
        }
    }

    // ---- per-block partials: psum/pss laid out [o][blk] for coalesced stats reads ----
    if (wv == 0) {
        float S  = s_red[0][lane][0] + s_red[1][lane][0] + s_red[2][lane][0] + s_red[3][lane][0];
        float SS = s_red[0][lane][1] + s_red[1][lane][1] + s_red[2][lane][1] + s_red[3][lane][1];
        psum[lane*NBLK + tile] = S;
        pss [lane*NBLK + tile] = SS;
    }
}

// Kernel 2: reduce 512 partials per (b,o) -> mean & rsqrt(var+eps)
__global__ __launch_bounds__(256) void stats_kernel(
    const float* __restrict__ psum, const float* __restrict__ pss,
    float* __restrict__ stats)
{
    __shared__ float2 red[256];
    int e = blockIdx.x;            // 0..127: b = e>>6, o = e&63
    int b = e >> 6, o = e & 63;
    int t = threadIdx.x;
    const float* ps = psum + o*NBLK + b*512;
    const float* pq = pss  + o*NBLK + b*512;
    float2 v;
    v.x = ps[t] + ps[t+256];
    v.y = pq[t] + pq[t+256];
    red[t] = v;
    __syncthreads();
    #pragma unroll
    for (int s = 128; s > 0; s >>= 1) {
        if (t < s) { red[t].x += red[t+s].x; red[t].y += red[t+s].y; }
        __syncthreads();
    }
    if (t == 0) {
        const float invN = 1.0f/16384.0f;
        float mean = red[0].x * invN;
        float var  = red[0].y * invN - mean*mean;
        stats[e*2+0] = mean;
        stats[e*2+1] = rsqrtf(var + 1e-5f);
    }
}

// Kernel 3: in-place instance norm + leaky relu, float4 elementwise
__global__ __launch_bounds__(256) void norm_kernel(
    float* __restrict__ out, const float* __restrict__ stats)
{
    int idx = blockIdx.x * 256 + threadIdx.x;   // float4 index; 524288 total
    float4* o4 = reinterpret_cast<float4*>(out);
    float4 v = o4[idx];
    int bo = idx >> 12;                          // 4096 float4 per (b,o) plane
    float mean = stats[bo*2 + 0];
    float r    = stats[bo*2 + 1];
    float a;
    a = (v.x - mean) * r; v.x = (a >= 0.f) ? a : 0.01f*a;
    a = (v.y - mean) * r; v.y = (a >= 0.f) ? a : 0.01f*a;
    a = (v.z - mean) * r; v.z = (a >= 0.f) ? a : 0.01f*a;
    a = (v.w - mean) * r; v.w = (a >= 0.f) ? a : 0.01f*a;
    o4[idx] = v;
}

extern "C" void kernel_launch(void* const* d_in, const int* in_sizes, int n_in,
                              void* d_out, int out_size, void* d_ws, size_t ws_size,
                              hipStream_t stream) {
    const float* x      = (const float*)d_in[0];
    const float* layout = (const float*)d_in[1];
    const float* pr     = (const float*)d_in[2];
    const float* cw     = (const float*)d_in[3];
    const float* cb     = (const float*)d_in[4];
    const float* Wt     = (const float*)d_in[5];
    const float* bt     = (const float*)d_in[6];
    const float* pl     = (const float*)d_in[7];
    float* out   = (float*)d_out;
    float* psum  = (float*)d_ws;                       // 64*1024 floats
    float* pss   = psum + (size_t)OO*NBLK;             // 64*1024 floats
    float* stats = pss  + (size_t)OO*NBLK;             // 128*2 floats

    ky_kernel<<<NBLK, 256, 0, stream>>>(x, layout, pr, cw, cb, Wt, bt, pl, out, psum, pss);
    stats_kernel<<<128, 256, 0, stream>>>(psum, pss, stats);
    norm_kernel<<<2048, 256, 0, stream>>>(out, stats);
}